// Round 1
// baseline (172.371 us; speedup 1.0000x reference)
//
#include <hip/hip_runtime.h>

// Problem constants (from reference setup_inputs):
//   pred (B=16, A=3, H=48, W=96, 5+C=85) fp32
//   anchors (3,2) fp32; txywh (256,4) fp32; t_b (256,) i32; t_cls (256,) i32
//   INPUT_DIM=384 -> stride_h = 384/48 = 8, stride_w = 768/96 = 8
#define TT   256
#define AA   3
#define HH   48
#define WW   96
#define BB   16
#define CC   80
#define DD   85
#define NCELL (BB*AA*HH*WW)   // 221184
#define NSUMBLK (NCELL/256)   // 864

__device__ __forceinline__ float softplusf(float z) {
    // stable: max(z,0) + log1p(exp(-|z|))
    return fmaxf(z, 0.0f) + log1pf(__expf(-fabsf(z)));
}

__global__ __launch_bounds__(256)
void yolo_loss_kernel(const float* __restrict__ pred,
                      const float* __restrict__ anchors,
                      const float* __restrict__ txywh,
                      const int*   __restrict__ t_b,
                      const int*   __restrict__ t_cls,
                      float*       __restrict__ out)
{
    __shared__ int   s_cell[TT];
    __shared__ int   s_cls[TT];
    __shared__ float s_red[4];

    const int tid = threadIdx.x;
    float acc = 0.0f;

    if (blockIdx.x < NSUMBLK) {
        // ---- full-grid no-obj term: 0.5 * softplus(z_obj) per cell ----
        const int cell = blockIdx.x * 256 + tid;          // 0..NCELL-1
        const float z  = pred[(size_t)cell * DD + 4];
        acc = 0.5f * softplusf(z);
    } else {
        // ---- target block: build targets + masked-cell corrections ----
        const int t = tid;                                 // one target per thread
        const float x = txywh[t*4 + 0] * (float)WW;
        const float y = txywh[t*4 + 1] * (float)HH;
        const float w = txywh[t*4 + 2] * 768.0f;           // INPUT_DIM*2
        const float h = txywh[t*4 + 3] * 384.0f;           // INPUT_DIM
        const bool valid = (x >= 0.0f) && (y >= 0.0f) &&
                           (x <= (float)(WW - 1)) && (y <= (float)(HH - 1));
        const int gx = min(max((int)floorf(x), 0), WW - 1);
        const int gy = min(max((int)floorf(y), 0), HH - 1);

        // best anchor by IoU (first max on ties, matching jnp.argmax)
        int best = 0; float bestr = -1.0f, bsw = 1.0f, bsh = 1.0f;
        #pragma unroll
        for (int a = 0; a < AA; ++a) {
            const float sw = anchors[a*2 + 0] * 8.0f;      // stride_w
            const float sh = anchors[a*2 + 1] * 8.0f;      // stride_h
            const float inter = fminf(w, sw) * fminf(h, sh);
            const float uni   = w*h + sw*sh - inter + 1e-16f;
            const float r = inter / uni;
            if (r > bestr) { bestr = r; best = a; bsw = sw; bsh = sh; }
        }
        const int b   = t_b[t];
        const int cls = t_cls[t];
        const int cell = ((b*AA + best)*HH + gy)*WW + gx;

        s_cell[t] = valid ? cell : -1;
        s_cls[t]  = cls;
        __syncthreads();

        if (valid) {
            // last-write-wins for the scalar targets; class one-hot is the
            // union of all colliding targets' classes (dedupe identical ones)
            bool winner = true, clsOwner = true;
            for (int u = t + 1; u < TT; ++u) {
                if (s_cell[u] == cell) {
                    winner = false;
                    if (s_cls[u] == cls) clsOwner = false;
                }
            }
            const float* p = pred + (size_t)cell * DD;
            if (winner) {
                const float tx = x - floorf(x);
                const float ty = y - floorf(y);
                const float tw = logf(w / bsw + 1e-16f);
                const float th = logf(h / bsh + 1e-16f);
                const float p0 = p[0], p1 = p[1], p2 = p[2], p3 = p[3], z = p[4];
                const float sx = 1.0f / (1.0f + __expf(-p0));
                const float sy = 1.0f / (1.0f + __expf(-p1));
                acc += (sx - tx)*(sx - tx) + (sy - ty)*(sy - ty)
                     + (p2 - tw)*(p2 - tw) + (p3 - th)*(p3 - th);
                // masked obj BCE replaces the 0.5*no-obj term counted globally
                acc += softplusf(-z) - 0.5f * softplusf(z);
                // class BCE base: sum_c softplus(z_c)
                float cs = 0.0f;
                for (int c = 0; c < CC; ++c) cs += softplusf(p[5 + c]);
                acc += cs;
            }
            // one-hot flip: softplus(-z_c*) - softplus(z_c*) = -z_c*
            if (clsOwner) acc -= p[5 + cls];
        }
    }

    // ---- block reduction -> one atomicAdd per block ----
    #pragma unroll
    for (int off = 32; off > 0; off >>= 1) acc += __shfl_down(acc, off, 64);
    const int lane = tid & 63, wid = tid >> 6;
    if (lane == 0) s_red[wid] = acc;
    __syncthreads();
    if (tid == 0) atomicAdd(out, s_red[0] + s_red[1] + s_red[2] + s_red[3]);
}

extern "C" void kernel_launch(void* const* d_in, const int* in_sizes, int n_in,
                              void* d_out, int out_size, void* d_ws, size_t ws_size,
                              hipStream_t stream) {
    const float* pred    = (const float*)d_in[0];
    const float* anchors = (const float*)d_in[1];
    const float* txywh   = (const float*)d_in[2];
    const int*   t_b     = (const int*)d_in[3];
    const int*   t_cls   = (const int*)d_in[4];
    float* out = (float*)d_out;

    // d_out is re-poisoned before every timed replay -> zero it ourselves.
    hipMemsetAsync(out, 0, sizeof(float), stream);

    yolo_loss_kernel<<<dim3(NSUMBLK + 1), dim3(256), 0, stream>>>(
        pred, anchors, txywh, t_b, t_cls, out);
}

// Round 2
// 166.360 us; speedup vs baseline: 1.0361x; 1.0361x over previous
//
#include <hip/hip_runtime.h>

// Problem constants (from reference setup_inputs):
//   pred (B=16, A=3, H=48, W=96, 5+C=85) fp32
//   anchors (3,2) fp32; txywh (256,4) fp32; t_b (256,) i32; t_cls (256,) i32
//   INPUT_DIM=384 -> stride_h = 384/48 = 8, stride_w = 768/96 = 8
#define TT   256
#define AA   3
#define HH   48
#define WW   96
#define BB   16
#define CC   80
#define DD   85
#define NCELL (BB*AA*HH*WW)        // 221184
#define CPT   4                    // cells per thread (independent loads -> MLP)
#define GBLK  (NCELL/(256*CPT))    // 216 gather blocks (216*1024 == 221184)
#define NPART (GBLK+1)             // 217 partial sums

__device__ __forceinline__ float softplusf(float z) {
    // stable: max(z,0) + log1p(exp(-|z|))
    return fmaxf(z, 0.0f) + log1pf(__expf(-fabsf(z)));
}

__device__ __forceinline__ float block_reduce(float acc, float* s_red, int tid) {
    #pragma unroll
    for (int off = 32; off > 0; off >>= 1) acc += __shfl_down(acc, off, 64);
    const int lane = tid & 63, wid = tid >> 6;
    if (lane == 0) s_red[wid] = acc;
    __syncthreads();
    return s_red[0] + s_red[1] + s_red[2] + s_red[3];
}

__global__ __launch_bounds__(256)
void yolo_partial_kernel(const float* __restrict__ pred,
                         const float* __restrict__ anchors,
                         const float* __restrict__ txywh,
                         const int*   __restrict__ t_b,
                         const int*   __restrict__ t_cls,
                         float*       __restrict__ partials)
{
    __shared__ int   s_cell[TT];
    __shared__ int   s_cls[TT];
    __shared__ float s_red[4];

    const int tid = threadIdx.x;
    float acc = 0.0f;

    if (blockIdx.x < GBLK) {
        // ---- full-grid no-obj term: 0.5 * softplus(z_obj) per cell ----
        const int base = blockIdx.x * (256 * CPT) + tid;
        float z[CPT];
        #pragma unroll
        for (int k = 0; k < CPT; ++k)
            z[k] = pred[(size_t)(base + 256 * k) * DD + 4];   // 4 independent loads
        #pragma unroll
        for (int k = 0; k < CPT; ++k)
            acc += 0.5f * softplusf(z[k]);
    } else {
        // ---- target block: build targets + masked-cell corrections ----
        const int t = tid;                                 // one target per thread
        const float x = txywh[t*4 + 0] * (float)WW;
        const float y = txywh[t*4 + 1] * (float)HH;
        const float w = txywh[t*4 + 2] * 768.0f;           // INPUT_DIM*2
        const float h = txywh[t*4 + 3] * 384.0f;           // INPUT_DIM
        const bool valid = (x >= 0.0f) && (y >= 0.0f) &&
                           (x <= (float)(WW - 1)) && (y <= (float)(HH - 1));
        const int gx = min(max((int)floorf(x), 0), WW - 1);
        const int gy = min(max((int)floorf(y), 0), HH - 1);

        // best anchor by IoU (first max on ties, matching jnp.argmax)
        int best = 0; float bestr = -1.0f, bsw = 1.0f, bsh = 1.0f;
        #pragma unroll
        for (int a = 0; a < AA; ++a) {
            const float sw = anchors[a*2 + 0] * 8.0f;      // stride_w
            const float sh = anchors[a*2 + 1] * 8.0f;      // stride_h
            const float inter = fminf(w, sw) * fminf(h, sh);
            const float uni   = w*h + sw*sh - inter + 1e-16f;
            const float r = inter / uni;
            if (r > bestr) { bestr = r; best = a; bsw = sw; bsh = sh; }
        }
        const int b   = t_b[t];
        const int cls = t_cls[t];
        const int cell = ((b*AA + best)*HH + gy)*WW + gx;

        s_cell[t] = valid ? cell : -1;
        s_cls[t]  = cls;
        __syncthreads();

        if (valid) {
            // last-write-wins for the scalar targets; class one-hot is the
            // union of all colliding targets' classes (dedupe identical ones)
            bool winner = true, clsOwner = true;
            for (int u = t + 1; u < TT; ++u) {
                if (s_cell[u] == cell) {
                    winner = false;
                    if (s_cls[u] == cls) clsOwner = false;
                }
            }
            const float* p = pred + (size_t)cell * DD;
            if (winner) {
                const float tx = x - floorf(x);
                const float ty = y - floorf(y);
                const float tw = logf(w / bsw + 1e-16f);
                const float th = logf(h / bsh + 1e-16f);
                const float p0 = p[0], p1 = p[1], p2 = p[2], p3 = p[3], z = p[4];
                const float sx = 1.0f / (1.0f + __expf(-p0));
                const float sy = 1.0f / (1.0f + __expf(-p1));
                acc += (sx - tx)*(sx - tx) + (sy - ty)*(sy - ty)
                     + (p2 - tw)*(p2 - tw) + (p3 - th)*(p3 - th);
                // masked obj BCE replaces the 0.5*no-obj term counted globally
                acc += softplusf(-z) - 0.5f * softplusf(z);
                // class BCE base: sum_c softplus(z_c)
                float cs = 0.0f;
                for (int c = 0; c < CC; ++c) cs += softplusf(p[5 + c]);
                acc += cs;
            }
            // one-hot flip: softplus(-z_c*) - softplus(z_c*) = -z_c*
            if (clsOwner) acc -= p[5 + cls];
        }
    }

    // ---- block reduction -> one plain store per block (atomic-free) ----
    const float tot = block_reduce(acc, s_red, tid);
    if (tid == 0) partials[blockIdx.x] = tot;
}

__global__ __launch_bounds__(256)
void yolo_final_kernel(const float* __restrict__ partials,
                       float*       __restrict__ out)
{
    __shared__ float s_red[4];
    const int tid = threadIdx.x;
    float acc = 0.0f;
    for (int i = tid; i < NPART; i += 256) acc += partials[i];
    const float tot = block_reduce(acc, s_red, tid);
    if (tid == 0) out[0] = tot;
}

extern "C" void kernel_launch(void* const* d_in, const int* in_sizes, int n_in,
                              void* d_out, int out_size, void* d_ws, size_t ws_size,
                              hipStream_t stream) {
    const float* pred    = (const float*)d_in[0];
    const float* anchors = (const float*)d_in[1];
    const float* txywh   = (const float*)d_in[2];
    const int*   t_b     = (const int*)d_in[3];
    const int*   t_cls   = (const int*)d_in[4];
    float* out      = (float*)d_out;
    float* partials = (float*)d_ws;   // NPART floats of scratch

    yolo_partial_kernel<<<dim3(NPART), dim3(256), 0, stream>>>(
        pred, anchors, txywh, t_b, t_cls, partials);
    yolo_final_kernel<<<dim3(1), dim3(256), 0, stream>>>(partials, out);
}